// Round 10
// baseline (128.478 us; speedup 1.0000x reference)
//
#include <hip/hip_runtime.h>
#include <math.h>

// ---------------------------------------------------------------------------
// LocalTransformerBlock2d: B=1, C=256, H=W=56 (N=3136), 8 heads x d=32,
// 7x7 local window. fp32 in/out; bf16 MFMA GEMMs.
// 2 stream-ordered kernels:
//   qkv (inline LN1 + inline qkv_w cvt + GEMM; extra blocks cvt pw/f1/f2)
//   attnmlp (attn+proj+LN2+fc1+gelu+fc2+resid; one 512-thr block / 16 px)
// Ledger: 2x~42us harness poison fills inside the timed window (~85us
// structural floor). R9 pipeline ~40us over 3 nodes; this round removes the
// prep node by folding LN1 + weight-cvt into the qkv GEMM blocks.
// ---------------------------------------------------------------------------

typedef unsigned int uint;
typedef unsigned short ushort;
typedef unsigned long long u64;
typedef __attribute__((ext_vector_type(8))) short short8;   // 8 bf16
typedef __attribute__((ext_vector_type(4))) float floatx4;  // MFMA acc
typedef __attribute__((ext_vector_type(4))) unsigned short ushort4v;

#define AS1(p) (const __attribute__((address_space(1))) void*)(p)
#define AS3(p) (__attribute__((address_space(3))) void*)(p)

__device__ __forceinline__ float bf2f(ushort u) {
  union { uint i; float f; } v; v.i = ((uint)u) << 16; return v.f;
}
__device__ __forceinline__ ushort f2bf(float f) {
  union { float f; uint i; } v; v.f = f;
  uint u = v.i;
  return (ushort)((u + 0x7fffu + ((u >> 16) & 1u)) >> 16);
}

__device__ __forceinline__ void compute64(const ushort* As, const ushort* Bs,
                                          int w, int lane, floatx4 acc[4]) {
  const int fm = lane & 15;
  const int q  = lane >> 4;
  const int swz = fm & 7;
  const int arow = (w * 16 + fm) * 256;
  #pragma unroll
  for (int kt = 0; kt < 8; ++kt) {
    const int blk = ((kt * 4 + q) ^ swz) * 8;
    short8 af = *(const short8*)&As[arow + blk];
    #pragma unroll
    for (int nt = 0; nt < 4; ++nt) {
      short8 bfr = *(const short8*)&Bs[(nt * 16 + fm) * 256 + blk];
      acc[nt] = __builtin_amdgcn_mfma_f32_16x16x32_bf16(af, bfr, acc[nt], 0, 0, 0);
    }
  }
}

// ---------------------------------------------------------------------------
// qkv: grid (12, 241). y<49: GEMM [3136,256]@[768,256]^T + bias (q scaled),
// with LN1 computed inline from x (wave w = 64-ch slice, lane = pixel) and
// qkv_w converted fp32->bf16 inline into the swizzled Bs tile.
// y>=49: cvt blocks for pw|f1|f2 (589824 elems), consumed by attnmlp.
// ---------------------------------------------------------------------------
__global__ __launch_bounds__(256, 2) void qkv_kernel(
    const float* __restrict__ x, const float* __restrict__ n1w,
    const float* __restrict__ n1b, const float* __restrict__ qkvw,
    const float* __restrict__ bias, ushort* __restrict__ out,
    const float* __restrict__ projw, const float* __restrict__ f1w,
    const float* __restrict__ f2w, ushort* __restrict__ wcat)
{
  const int tid = threadIdx.x;
  if (blockIdx.y >= 49) {
    int c = (blockIdx.y - 49) * 12 + blockIdx.x;     // 0..2303
    int idx = c * 256 + tid;                         // < 589824
    float v;
    if (idx < 65536)        v = projw[idx];
    else if (idx < 327680)  v = f1w[idx - 65536];
    else                    v = f2w[idx - 327680];
    wcat[196608 + idx] = f2bf(v);
    return;
  }
  __shared__ ushort As[16384], Bs[16384];
  __shared__ float psum[4][64], psumsq[4][64];
  const int lane = tid & 63, w = tid >> 6;
  const int m0 = blockIdx.y * 64, n0 = blockIdx.x * 64;

  // ---- Phase A1: wave w loads channels [64w,64w+64) of pixel m0+lane ----
  float arr[64];
  {
    const float* xp = x + (size_t)(w * 64) * 3136 + m0 + lane;  // coalesced
    float s = 0.f, ss = 0.f;
    #pragma unroll
    for (int i = 0; i < 64; ++i) {
      float v = xp[(size_t)i * 3136];
      arr[i] = v;
      s += v; ss += v * v;
    }
    psum[w][lane] = s;
    psumsq[w][lane] = ss;
  }

  // ---- Phase B: qkv_w rows [n0,n0+64) fp32 -> Bs bf16 (XOR swizzle) ----
  #pragma unroll
  for (int k = 0; k < 8; ++k) {
    int srow = k * 8 + (tid >> 5);
    int cb = tid & 31;
    int gb = cb ^ (srow & 7);
    const float* gp = qkvw + (size_t)(n0 + srow) * 256 + gb * 8;
    floatx4 a = *(const floatx4*)gp;
    floatx4 b = *(const floatx4*)(gp + 4);
    short8 o;
    #pragma unroll
    for (int e = 0; e < 4; ++e) {
      o[e]     = (short)f2bf(a[e]);
      o[e + 4] = (short)f2bf(b[e]);
    }
    *(short8*)&Bs[srow * 256 + cb * 8] = o;
  }
  __syncthreads();   // psum visible (Bs also done; read after next barrier)

  // ---- Phase A2: stats + normalize -> As (bf16, swizzled) ----
  {
    float s  = psum[0][lane] + psum[1][lane] + psum[2][lane] + psum[3][lane];
    float ss = psumsq[0][lane] + psumsq[1][lane] + psumsq[2][lane] + psumsq[3][lane];
    float mu = s * (1.f / 256.f);
    float var = ss * (1.f / 256.f) - mu * mu;
    float rsv = rsqrtf(var + 1e-5f);
    #pragma unroll
    for (int g = 0; g < 8; ++g) {
      short8 o;
      #pragma unroll
      for (int e = 0; e < 8; ++e) {
        int ch = w * 64 + g * 8 + e;                 // wave-uniform -> s_load
        o[e] = (short)f2bf((arr[g * 8 + e] - mu) * rsv * n1w[ch] + n1b[ch]);
      }
      int gblk = w * 8 + g;
      *(short8*)&As[lane * 256 + ((gblk ^ (lane & 7)) * 8)] = o;
    }
  }
  __syncthreads();   // As complete (all waves' ch-slices)

  floatx4 acc[4] = {{0.f,0.f,0.f,0.f},{0.f,0.f,0.f,0.f},
                    {0.f,0.f,0.f,0.f},{0.f,0.f,0.f,0.f}};
  compute64(As, Bs, w, lane, acc);
  const int fm = lane & 15, q4 = (lane >> 4) * 4;
  #pragma unroll
  for (int nt = 0; nt < 4; ++nt)
    #pragma unroll
    for (int r = 0; r < 4; ++r) {
      int m = m0 + w * 16 + q4 + r;
      int n = n0 + nt * 16 + fm;
      float v = acc[nt][r] + bias[n];
      if (n < 256) v *= 0.17677669529663687f;   // 1/sqrt(32) on q
      out[(size_t)m * 768 + n] = f2bf(v);
    }
}

// ---------------------------------------------------------------------------
// attnmlp: 4x4 query tile per block (grid 196), 512 threads (2 waves/SIMD).
// LDS (byte offsets):
//  attn: Kh@0 (52000) | Vh@52000 (51200) | pr@103200 f32 stride67 (34304)
//        aas@137504 (8448)
//  proj: pslab@0 (Kh dead) | x1s@103200 f32[16][264] (pr dead)
//  mlp : hbuf@0 (32768) | fslab@32768 (65536) | t2s@120096 (8192)
//        pstat@128288 | stats@129312
// ---------------------------------------------------------------------------
#define AM_SMEM 145952

__global__ __launch_bounds__(512, 1) void attnmlp_kernel(
    const ushort* __restrict__ qkv, const ushort* __restrict__ pw_bf,
    const float* __restrict__ projb, const float* __restrict__ x,
    const ushort* __restrict__ f1_bf, const float* __restrict__ f1b,
    const ushort* __restrict__ f2_bf, const float* __restrict__ f2b,
    const float* __restrict__ n2w, const float* __restrict__ n2b,
    float* __restrict__ outf)
{
  __shared__ __align__(16) char smem[AM_SMEM];
  ushort* Kh    = (ushort*)smem;
  ushort* Vh    = (ushort*)(smem + 52000);
  float*  pr    = (float*)(smem + 103200);       // [16*8][67]
  ushort* aas   = (ushort*)(smem + 137504);      // [16][264]
  ushort* pslab = (ushort*)smem;                 // proj slabs (Kh dead)
  float*  x1s   = (float*)(smem + 103200);       // [16][264] f32 (pr dead)
  ushort* hbuf  = (ushort*)smem;                 // [16][1024]
  ushort* fslab = (ushort*)(smem + 32768);       // 8 x 4096 elems
  ushort* t2s   = (ushort*)(smem + 120096);      // [16][256]
  float*  pstat = (float*)(smem + 128288);       // [8][16][2]
  float*  stats = (float*)(smem + 129312);       // [16][2]

  const int tid = threadIdx.x;
  const int wv = tid >> 6, lane = tid & 63;
  const int fm = lane & 15, q = lane >> 4;
  const int l4 = lane >> 2, lb = lane & 3;
  const int i0 = (blockIdx.x / 14) * 4, j0 = (blockIdx.x % 14) * 4;

  // ---- halo load (zero-fill out-of-image) ----
  for (int s = tid; s < 3200; s += 512) {
    int p = s >> 5, ck = s & 31;
    int ii = i0 - 3 + p / 10, jj = j0 - 3 + p % 10;
    if (ii >= 0 && ii < 56 && jj >= 0 && jj < 56) {
      const ushort* kr = qkv + (size_t)(ii * 56 + jj) * 768 + 256 + ck * 8;
      short8 kv = *(const short8*)kr;
      u64 lo = ((const u64*)&kv)[0], hi = ((const u64*)&kv)[1];
      *(u64*)&Kh[p * 260 + ck * 8] = lo;
      *(u64*)&Kh[p * 260 + ck * 8 + 4] = hi;
      *(short8*)&Vh[p * 256 + ck * 8] = *(const short8*)(kr + 256);
    } else {
      *(u64*)&Kh[p * 260 + ck * 8] = 0ull;
      *(u64*)&Kh[p * 260 + ck * 8 + 4] = 0ull;
      short8 z = {0, 0, 0, 0, 0, 0, 0, 0};
      *(short8*)&Vh[p * 256 + ck * 8] = z;
    }
  }
  __syncthreads();

  // ---- scores + softmax: wave wv owns queries 2wv, 2wv+1 ----
  {
    const int h = lane >> 3, mg = lane & 7;
    #pragma unroll
    for (int qq = 0; qq < 2; ++qq) {
      const int p = wv * 2 + qq;
      const int qi = p >> 2, qj = p & 3;
      const int iq = i0 + qi, jq = j0 + qj;
      const ushort* qp = qkv + (size_t)(iq * 56 + jq) * 768 + h * 32;
      float qf[32];
      #pragma unroll
      for (int u = 0; u < 4; ++u) {
        short8 qv = *(const short8*)(qp + u * 8);
        #pragma unroll
        for (int e = 0; e < 8; ++e) qf[u * 8 + e] = bf2f((ushort)qv[e]);
      }
      float sv[7];
      float mx = -1e30f;
      #pragma unroll
      for (int k = 0; k < 7; ++k) {
        int m = mg + 8 * k;
        float s = -1e30f;
        if (m < 49) {
          int mi = m / 7, mj = m % 7;
          int ii = iq + mi - 3, jj = jq + mj - 3;
          if (ii >= 0 && ii < 56 && jj >= 0 && jj < 56) {
            int hrow = (qi + mi) * 10 + (qj + mj);
            const u64* k8 = (const u64*)&Kh[hrow * 260 + h * 32];
            float a = 0.f;
            #pragma unroll
            for (int u = 0; u < 8; ++u) {
              u64 kv = k8[u];
              #pragma unroll
              for (int e = 0; e < 4; ++e)
                a += qf[u * 4 + e] * bf2f((ushort)(kv >> (16 * e)));
            }
            s = a;
          }
        }
        sv[k] = s;
        mx = fmaxf(mx, s);
      }
      mx = fmaxf(mx, __shfl_xor(mx, 1));
      mx = fmaxf(mx, __shfl_xor(mx, 2));
      mx = fmaxf(mx, __shfl_xor(mx, 4));
      float sm = 0.f;
      #pragma unroll
      for (int k = 0; k < 7; ++k) { sv[k] = __expf(sv[k] - mx); sm += sv[k]; }
      sm += __shfl_xor(sm, 1);
      sm += __shfl_xor(sm, 2);
      sm += __shfl_xor(sm, 4);
      float inv = 1.f / sm;
      #pragma unroll
      for (int k = 0; k < 7; ++k) {
        int m = mg + 8 * k;
        pr[(p * 8 + h) * 67 + m] = sv[k] * inv;
      }
    }
  }
  __syncthreads();     // Kh dead; pr visible

  // per-wave proj slab dbuf in dead Kh region
  ushort* ps0 = pslab + wv * 2048;
  ushort* ps1 = ps0 + 1024;
#define STAGE_P(kt, buf) do { \
    _Pragma("unroll") \
    for (int i_ = 0; i_ < 2; ++i_) { \
      int row_ = i_ * 16 + l4; \
      const ushort* g_ = pw_bf + (size_t)(wv * 32 + row_) * 256 + (kt) * 32 + (lb ^ (row_ & 3)) * 8; \
      __builtin_amdgcn_global_load_lds(AS1(g_), AS3((buf) + i_ * 512 + lane * 8), 16, 0, 0); \
    } } while (0)
  STAGE_P(0, ps0);     // overlaps PV compute

  // ---- PV: thread = (query p = tid>>5, 8-ch group cg), single pass ----
  {
    const int p = tid >> 5, cg = tid & 31, hh = cg >> 2;
    const int qi = p >> 2, qj = p & 3;
    float acc8[8] = {0, 0, 0, 0, 0, 0, 0, 0};
    #pragma unroll
    for (int mi = 0; mi < 7; ++mi)
      #pragma unroll
      for (int mj = 0; mj < 7; ++mj) {
        int m = mi * 7 + mj;
        int hrow = (qi + mi) * 10 + (qj + mj);
        float pm = pr[(p * 8 + hh) * 67 + m];
        short8 v8 = *(const short8*)&Vh[hrow * 256 + cg * 8];
        #pragma unroll
        for (int e = 0; e < 8; ++e)
          acc8[e] += pm * bf2f((ushort)v8[e]);
      }
    short8 o;
    #pragma unroll
    for (int e = 0; e < 8; ++e) o[e] = (short)f2bf(acc8[e]);
    *(short8*)&aas[p * 264 + cg * 8] = o;
  }
  __syncthreads();     // aas visible; pr/Vh dead after this phase

  // ---- proj: wave wv -> out ch wv*32..+31, all 16 px; resid from x ----
  {
    floatx4 pacc[2] = {{0.f,0.f,0.f,0.f},{0.f,0.f,0.f,0.f}};
    for (int kt = 0; kt < 8; ++kt) {
      ushort* cur = (kt & 1) ? ps1 : ps0;
      ushort* nxt = (kt & 1) ? ps0 : ps1;
      if (kt < 7) {
        STAGE_P(kt + 1, nxt);
        asm volatile("s_waitcnt vmcnt(2)" ::: "memory");
      } else {
        asm volatile("s_waitcnt vmcnt(0)" ::: "memory");
      }
      short8 af = *(const short8*)&aas[fm * 264 + kt * 32 + q * 8];
      #pragma unroll
      for (int nt = 0; nt < 2; ++nt) {
        int r = nt * 16 + fm;
        short8 bfr = *(const short8*)&cur[r * 32 + (q ^ (r & 3)) * 8];
        pacc[nt] = __builtin_amdgcn_mfma_f32_16x16x32_bf16(af, bfr, pacc[nt], 0, 0, 0);
      }
    }
    #pragma unroll
    for (int nt = 0; nt < 2; ++nt) {
      int ch = wv * 32 + nt * 16 + fm;
      floatx4 rx = *(const floatx4*)(x + (size_t)ch * 3136 + (i0 + q) * 56 + j0);
      #pragma unroll
      for (int r = 0; r < 4; ++r) {
        int px = q * 4 + r;
        x1s[px * 264 + ch] = pacc[nt][r] + projb[ch] + rx[r];
      }
    }
  }
  // kick fc1 slab 0 (fslab region: dead Kh/Vh); lands across the barrier
  ushort* fs0 = fslab + wv * 4096;
  ushort* fs1 = fs0 + 2048;
#define STAGE_F1(c, kt, buf) do { \
    _Pragma("unroll") \
    for (int i_ = 0; i_ < 4; ++i_) { \
      int row_ = i_ * 16 + l4; \
      const ushort* g_ = f1_bf + (size_t)((c) * 64 + row_) * 256 + (kt) * 32 + (lb ^ (row_ & 3)) * 8; \
      __builtin_amdgcn_global_load_lds(AS1(g_), AS3((buf) + i_ * 512 + lane * 8), 16, 0, 0); \
    } } while (0)
  STAGE_F1(wv, 0, fs0);
  __syncthreads();     // x1s complete

  // ---- LN2 from x1s; residual kept in regs (matches fc2 acc layout) ----
  floatx4 xv[2];
  xv[0] = *(const floatx4*)&x1s[fm * 264 + wv * 32 + q * 4];
  xv[1] = *(const floatx4*)&x1s[fm * 264 + wv * 32 + 16 + q * 4];
  {
    float s = 0.f, ss = 0.f;
    #pragma unroll
    for (int nt = 0; nt < 2; ++nt)
      #pragma unroll
      for (int e = 0; e < 4; ++e) { s += xv[nt][e]; ss += xv[nt][e] * xv[nt][e]; }
    s += __shfl_xor(s, 16); ss += __shfl_xor(ss, 16);
    s += __shfl_xor(s, 32); ss += __shfl_xor(ss, 32);
    if (lane < 16) { pstat[(wv * 16 + lane) * 2] = s; pstat[(wv * 16 + lane) * 2 + 1] = ss; }
  }
  __syncthreads();
  if (tid < 16) {
    float s2 = 0.f, ss2 = 0.f;
    #pragma unroll
    for (int ww = 0; ww < 8; ++ww) {
      s2 += pstat[(ww * 16 + tid) * 2];
      ss2 += pstat[(ww * 16 + tid) * 2 + 1];
    }
    float mu = s2 * (1.f / 256.f);
    float var = ss2 * (1.f / 256.f) - mu * mu;
    stats[tid * 2] = mu;
    stats[tid * 2 + 1] = rsqrtf(var + 1e-5f);
  }
  __syncthreads();
  {
    float mu = stats[fm * 2], rs = stats[fm * 2 + 1];
    #pragma unroll
    for (int nt = 0; nt < 2; ++nt) {
      int ch0 = wv * 32 + nt * 16 + q * 4;
      ushort4v o;
      #pragma unroll
      for (int e = 0; e < 4; ++e)
        o[e] = f2bf((xv[nt][e] - mu) * rs * n2w[ch0 + e] + n2b[ch0 + e]);
      int slot = ch0 >> 3;
      *(ushort4v*)&t2s[fm * 256 + ((slot ^ (fm & 7)) * 8) + (ch0 & 7)] = o;
    }
  }
  // preload fc1 bias for this wave's chunks {wv, wv+8}
  float f1br[2][4];
  #pragma unroll
  for (int ci = 0; ci < 2; ++ci)
    #pragma unroll
    for (int nt = 0; nt < 4; ++nt)
      f1br[ci][nt] = f1b[(wv + ci * 8) * 64 + nt * 16 + fm];
  __syncthreads();     // t2s complete

  // ---- fc1: wave wv -> h chunks {wv, wv+8} (64 cols each), gelu -> hbuf ----
  {
    floatx4 fa[4] = {{0.f,0.f,0.f,0.f},{0.f,0.f,0.f,0.f},
                     {0.f,0.f,0.f,0.f},{0.f,0.f,0.f,0.f}};
    for (int sidx = 0; sidx < 16; ++sidx) {
      const int kt = sidx & 7;
      const int ci = sidx >> 3;
      ushort* cur = (sidx & 1) ? fs1 : fs0;
      ushort* nxt = (sidx & 1) ? fs0 : fs1;
      if (sidx < 15) {
        int s1 = sidx + 1;
        STAGE_F1(wv + (s1 >> 3) * 8, s1 & 7, nxt);
        asm volatile("s_waitcnt vmcnt(4)" ::: "memory");
      } else {
        asm volatile("s_waitcnt vmcnt(0)" ::: "memory");
      }
      short8 af = *(const short8*)&t2s[fm * 256 + (((kt * 4 + q) ^ (fm & 7)) * 8)];
      #pragma unroll
      for (int nt = 0; nt < 4; ++nt) {
        int r = nt * 16 + fm;
        short8 bfr = *(const short8*)&cur[r * 32 + (q ^ (r & 3)) * 8];
        fa[nt] = __builtin_amdgcn_mfma_f32_16x16x32_bf16(af, bfr, fa[nt], 0, 0, 0);
      }
      if (kt == 7) {
        #pragma unroll
        for (int nt = 0; nt < 4; ++nt) {
          int hc = (wv + ci * 8) * 64 + nt * 16 + fm;
          #pragma unroll
          for (int r4 = 0; r4 < 4; ++r4) {
            int prow = q * 4 + r4;
            float v = fa[nt][r4] + f1br[ci][nt];
            v = 0.5f * v * (1.0f + erff(v * 0.70710678118654752f));
            hbuf[prow * 1024 + (((hc >> 3) ^ (prow & 7)) * 8) + (hc & 7)] = f2bf(v);
            fa[nt][r4] = 0.f;
          }
        }
      }
    }
  }
  // kick fc2 slab 0 into this wave's (now idle) slab region
  ushort* gs0 = fs0;
  ushort* gs1 = fs0 + 1024;
#define STAGE_F2(kt, buf) do { \
    _Pragma("unroll") \
    for (int i_ = 0; i_ < 2; ++i_) { \
      int row_ = i_ * 16 + l4; \
      const ushort* g_ = f2_bf + (size_t)(wv * 32 + row_) * 1024 + (kt) * 32 + (lb ^ (row_ & 3)) * 8; \
      __builtin_amdgcn_global_load_lds(AS1(g_), AS3((buf) + i_ * 512 + lane * 8), 16, 0, 0); \
    } } while (0)
  STAGE_F2(0, gs0);
  __syncthreads();     // hbuf complete

  // ---- fc2: wave wv -> out channels wv*32..+31; residual from regs ----
  {
    floatx4 ga[2] = {{0.f,0.f,0.f,0.f},{0.f,0.f,0.f,0.f}};
    for (int kt = 0; kt < 32; ++kt) {
      ushort* cur = (kt & 1) ? gs1 : gs0;
      ushort* nxt = (kt & 1) ? gs0 : gs1;
      if (kt < 31) {
        STAGE_F2(kt + 1, nxt);
        asm volatile("s_waitcnt vmcnt(2)" ::: "memory");
      } else {
        asm volatile("s_waitcnt vmcnt(0)" ::: "memory");
      }
      short8 bfr = *(const short8*)&hbuf[fm * 1024 + (((kt * 4 + q) ^ (fm & 7)) * 8)];
      #pragma unroll
      for (int mt = 0; mt < 2; ++mt) {
        int r = mt * 16 + fm;
        short8 af = *(const short8*)&cur[r * 32 + (q ^ (r & 3)) * 8];
        ga[mt] = __builtin_amdgcn_mfma_f32_16x16x32_bf16(af, bfr, ga[mt], 0, 0, 0);
      }
    }
    #pragma unroll
    for (int mt = 0; mt < 2; ++mt) {
      #pragma unroll
      for (int r4 = 0; r4 < 4; ++r4) {
        int ch = wv * 32 + mt * 16 + q * 4 + r4;
        int n = (i0 + (fm >> 2)) * 56 + j0 + (fm & 3);
        outf[(size_t)ch * 3136 + n] = ga[mt][r4] + f2b[ch] + xv[mt][r4];
      }
    }
  }
#undef STAGE_P
#undef STAGE_F1
#undef STAGE_F2
}

// ---------------------------------------------------------------------------
extern "C" void kernel_launch(void* const* d_in, const int* in_sizes, int n_in,
                              void* d_out, int out_size, void* d_ws, size_t ws_size,
                              hipStream_t stream) {
  const float* x     = (const float*)d_in[0];
  const float* n1w   = (const float*)d_in[1];
  const float* n1b   = (const float*)d_in[2];
  const float* qkvw  = (const float*)d_in[3];
  const float* qkvb  = (const float*)d_in[4];
  const float* projw = (const float*)d_in[5];
  const float* projb = (const float*)d_in[6];
  const float* n2w   = (const float*)d_in[7];
  const float* n2b   = (const float*)d_in[8];
  const float* f1w   = (const float*)d_in[9];
  const float* f1b   = (const float*)d_in[10];
  const float* f2w   = (const float*)d_in[11];
  const float* f2b   = (const float*)d_in[12];

  char* ws = (char*)d_ws;
  ushort* wcat = (ushort*)(ws + 0);            // bf16 weights (pw/f1/f2 region used)
  ushort* qh   = (ushort*)(ws + 6389760);      // qkv [3136][768]

  const ushort* pw_bf = wcat + 196608;
  const ushort* f1_bf = wcat + 262144;
  const ushort* f2_bf = wcat + 524288;
  float* outf = (float*)d_out;

  hipLaunchKernelGGL(qkv_kernel, dim3(12, 241), dim3(256), 0, stream,
                     x, n1w, n1b, qkvw, qkvb, qh, projw, f1w, f2w, wcat);
  hipLaunchKernelGGL(attnmlp_kernel, dim3(196), dim3(512), 0, stream,
                     qh, pw_bf, projb, x, f1_bf, f1b, f2_bf, f2b,
                     n2w, n2b, outf);
}